// Round 1
// baseline (403.892 us; speedup 1.0000x reference)
//
#include <hip/hip_runtime.h>
#include <cmath>

namespace {

constexpr int D = 64;       // head dim
constexpr int CHUNK = 64;   // tokens per block (= max segment size, r=4)
constexpr int PITCH = 68;   // LDS row pitch (floats), +4 pad keeps 16B alignment

__global__ __launch_bounds__(256)
void dilated_attn(const float* __restrict__ Q, const float* __restrict__ K,
                  const float* __restrict__ V, float* __restrict__ O) {
  __shared__ float Ks[CHUNK * PITCH];
  __shared__ float Vs[CHUNK * PITCH];

  const int c = blockIdx.x;            // global chunk id, 8192 total
  const int tid = threadIdx.x;
  const int bn = c >> 7;               // (b*16 + h); 128 chunks per sequence
  const int h = bn & 15;               // head index
  const int chunk_in_seq = c & 127;
  const size_t base = (size_t)c * (CHUNK * D);   // float offset of this chunk

  // ---- stage K,V chunk into LDS (fully coalesced float4 loads) ----
  const float4* gK = (const float4*)(K + base);
  const float4* gV = (const float4*)(V + base);
#pragma unroll
  for (int i = 0; i < 4; ++i) {
    int flat4 = i * 256 + tid;         // 0..1023 float4s = 64x64 floats
    int row = flat4 >> 4;
    int c4 = flat4 & 15;
    float4 kv = gK[flat4];
    float4 vv = gV[flat4];
    *(float4*)&Ks[row * PITCH + c4 * 4] = kv;
    *(float4*)&Vs[row * PITCH + c4 * 4] = vv;
  }

  // thread = (token t64 in chunk) x (dim group g of 16 floats)
  const int t64 = tid >> 2;
  const int g = tid & 3;

  // ---- Q fragment straight from global into registers ----
  float qreg[16];
  {
    const float4* gQ = (const float4*)(Q + base + (size_t)(t64 * D + g * 16));
#pragma unroll
    for (int i = 0; i < 4; ++i) {
      float4 v = gQ[i];
      qreg[4 * i + 0] = v.x; qreg[4 * i + 1] = v.y;
      qreg[4 * i + 2] = v.z; qreg[4 * i + 3] = v.w;
    }
  }

  float ot[16];
#pragma unroll
  for (int i = 0; i < 16; ++i) ot[i] = 0.f;

  __syncthreads();

  const int tglob = (chunk_in_seq << 6) + t64;   // token index within sequence

  // ---- four rates; all K/V needed are inside this chunk ----
#pragma unroll
  for (int r = 1; r <= 4; ++r) {
    const int logS = r + 2;            // S = 8,16,32,64
    const int S = 1 << logS;
    const int dmask = (1 << r) - 1;    // dilation dr - 1
    if (((tglob >> logS) & dmask) == (h & dmask)) {
      const int seg_q = t64 & (S - 1); // query pos within segment
      const int s0 = t64 - seg_q;      // segment start row in chunk
      float m = -INFINITY, l = 0.f;
      float oa[16];
#pragma unroll
      for (int i = 0; i < 16; ++i) oa[i] = 0.f;
      for (int j = 0; j <= seg_q; ++j) {
        const float* kr = &Ks[(s0 + j) * PITCH + g * 16];
        const float4 k0 = *(const float4*)(kr);
        const float4 k1 = *(const float4*)(kr + 4);
        const float4 k2 = *(const float4*)(kr + 8);
        const float4 k3 = *(const float4*)(kr + 12);
        float p = qreg[0] * k0.x;
        p = fmaf(qreg[1], k0.y, p);  p = fmaf(qreg[2], k0.z, p);
        p = fmaf(qreg[3], k0.w, p);  p = fmaf(qreg[4], k1.x, p);
        p = fmaf(qreg[5], k1.y, p);  p = fmaf(qreg[6], k1.z, p);
        p = fmaf(qreg[7], k1.w, p);  p = fmaf(qreg[8], k2.x, p);
        p = fmaf(qreg[9], k2.y, p);  p = fmaf(qreg[10], k2.z, p);
        p = fmaf(qreg[11], k2.w, p); p = fmaf(qreg[12], k3.x, p);
        p = fmaf(qreg[13], k3.y, p); p = fmaf(qreg[14], k3.z, p);
        p = fmaf(qreg[15], k3.w, p);
        // reduce partial dot across the 4 dim-group lanes (adjacent lanes)
        p += __shfl_xor(p, 1);
        p += __shfl_xor(p, 2);
        const float s = p * 0.125f;           // 1/sqrt(64)
        const float mn = fmaxf(m, s);
        const float fac = __expf(m - mn);     // first iter: exp(-inf)=0
        const float w = __expf(s - mn);
        l = l * fac + w;
        const float* vr = &Vs[(s0 + j) * PITCH + g * 16];
        const float4 v0 = *(const float4*)(vr);
        const float4 v1 = *(const float4*)(vr + 4);
        const float4 v2 = *(const float4*)(vr + 8);
        const float4 v3 = *(const float4*)(vr + 12);
        oa[0]  = fmaf(oa[0],  fac, w * v0.x);
        oa[1]  = fmaf(oa[1],  fac, w * v0.y);
        oa[2]  = fmaf(oa[2],  fac, w * v0.z);
        oa[3]  = fmaf(oa[3],  fac, w * v0.w);
        oa[4]  = fmaf(oa[4],  fac, w * v1.x);
        oa[5]  = fmaf(oa[5],  fac, w * v1.y);
        oa[6]  = fmaf(oa[6],  fac, w * v1.z);
        oa[7]  = fmaf(oa[7],  fac, w * v1.w);
        oa[8]  = fmaf(oa[8],  fac, w * v2.x);
        oa[9]  = fmaf(oa[9],  fac, w * v2.y);
        oa[10] = fmaf(oa[10], fac, w * v2.z);
        oa[11] = fmaf(oa[11], fac, w * v2.w);
        oa[12] = fmaf(oa[12], fac, w * v3.x);
        oa[13] = fmaf(oa[13], fac, w * v3.y);
        oa[14] = fmaf(oa[14], fac, w * v3.z);
        oa[15] = fmaf(oa[15], fac, w * v3.w);
        m = mn;
      }
      const float inv = 1.f / l;
#pragma unroll
      for (int i = 0; i < 16; ++i) ot[i] = fmaf(oa[i], inv, ot[i]);
    }
  }

  // ---- write output (each element written exactly once) ----
  float4* gO = (float4*)(O + base + (size_t)(t64 * D + g * 16));
#pragma unroll
  for (int i = 0; i < 4; ++i) {
    float4 v;
    v.x = ot[4 * i + 0] * 0.25f;
    v.y = ot[4 * i + 1] * 0.25f;
    v.z = ot[4 * i + 2] * 0.25f;
    v.w = ot[4 * i + 3] * 0.25f;
    gO[i] = v;
  }
}

} // namespace

extern "C" void kernel_launch(void* const* d_in, const int* in_sizes, int n_in,
                              void* d_out, int out_size, void* d_ws, size_t ws_size,
                              hipStream_t stream) {
  const float* Q = (const float*)d_in[0];
  const float* K = (const float*)d_in[1];
  const float* V = (const float*)d_in[2];
  float* O = (float*)d_out;
  const int blocks = out_size / (CHUNK * D);   // 4*16*8192*64 / 4096 = 8192
  dilated_attn<<<blocks, 256, 0, stream>>>(Q, K, V, O);
}